// Round 4
// baseline (81.282 us; speedup 1.0000x reference)
//
#include <hip/hip_runtime.h>

// BinaryLinearLayer: C = (sign(X) @ sign(W)) * (relu(alpha)*outer(relu(betta),relu(gamma))).flatten()
// M=8192, K=4096, N=2048.
// fp4 e2m1 (+/-1, 0 exact; unit E8M0 scales) -> mfma_scale_f32_32x32x64_f8f6f4.
// Operands stored SLOT-MAJOR per 256x256k tile: [panel][kt][slot 0..7][row 0..255] x 16B,
// so GEMM staging is a linear 32KB block copy and ds_reads are contiguous 512B
// per half-wave (bank-conflict-free, no swizzle arithmetic).

#define M_DIM 8192
#define K_DIM 4096
#define N_DIM 2048
#define NT    (K_DIM / 256)   // 16 K-tiles of 256 k-elems
#define TILE_BYTES 32768      // 8 slots x 256 rows x 16 B
#define PANEL_BYTES (NT * TILE_BYTES)  // 512 KB per 256-row panel

typedef int i32x4 __attribute__((ext_vector_type(4)));
typedef int i32x8 __attribute__((ext_vector_type(8)));
typedef float f32x16 __attribute__((ext_vector_type(16)));

__device__ __forceinline__ unsigned int nib4(float x) {
  // sign(x) as fp4 e2m1 nibble: +1 -> 0x2, -1 -> 0xA, 0 -> 0x0
  unsigned int s = (__float_as_uint(x) >> 28) & 0x8u;
  return x == 0.0f ? 0u : (0x2u | s);
}

__device__ __forceinline__ unsigned int pack8(const float* f) {
  unsigned int p = 0;
#pragma unroll
  for (int j = 0; j < 8; ++j) p |= nib4(f[j]) << (4 * j);
  return p;
}

__device__ __forceinline__ void gload_lds16(const void* g, void* lds) {
  __builtin_amdgcn_global_load_lds(
      (const __attribute__((address_space(1))) unsigned int*)g,
      (__attribute__((address_space(3))) unsigned int*)lds, 16, 0, 0);
}

__device__ __forceinline__ i32x8 pad8(i32x4 v) {
  i32x8 r;
  r[0] = v[0]; r[1] = v[1]; r[2] = v[2]; r[3] = v[3];
  r[4] = 0; r[5] = 0; r[6] = 0; r[7] = 0;
  return r;
}

// ---- fused binarize: X -> Xq (slot-major), W -> Wq (transpose, slot-major) ----
// blocks [0,512): X panel p = bid>>4, ktile = bid&15
// blocks [512,640): W panel q = (bid-512)>>4, ktile = (bid-512)&15
__global__ __launch_bounds__(256) void binXW_kernel(
    const float* __restrict__ X, const float* __restrict__ W,
    unsigned char* __restrict__ Xq, unsigned char* __restrict__ Wq) {
  __shared__ float tile[32][257];
  const int t = threadIdx.x;
  const int bid = blockIdx.x;

  if (bid < 512) {
    const int p = bid >> 4;
    const int kt = bid & 15;
    const float* Xrow = X + (size_t)(p * 256 + t) * K_DIM + kt * 256;
    unsigned char* dst = Xq + (size_t)p * PANEL_BYTES + kt * TILE_BYTES;
#pragma unroll
    for (int s = 0; s < 8; ++s) {
      float f[32];
#pragma unroll
      for (int i = 0; i < 8; ++i)
        *(float4*)&f[i * 4] = *(const float4*)&Xrow[s * 32 + i * 4];
      uint4 gq;
      gq.x = pack8(f + 0);  gq.y = pack8(f + 8);
      gq.z = pack8(f + 16); gq.w = pack8(f + 24);
      *(uint4*)&dst[(s * 256 + t) * 16] = gq;
    }
  } else {
    const int idx = bid - 512;
    const int q = idx >> 4;
    const int kt = idx & 15;
    unsigned char* dst = Wq + (size_t)q * PANEL_BYTES + kt * TILE_BYTES;
    for (int s = 0; s < 8; ++s) {
      // load stripe W[kt*256 + s*32 + 0..31][q*256 + 0..255] into LDS
#pragma unroll
      for (int it = 0; it < 8; ++it) {
        int row = it * 4 + (t >> 6);
        int col4 = (t & 63) * 4;
        *(float4*)&tile[row][col4] =
            *(const float4*)&W[(size_t)(kt * 256 + s * 32 + row) * N_DIM + q * 256 + col4];
      }
      __syncthreads();
      float f[32];
#pragma unroll
      for (int k = 0; k < 32; ++k) f[k] = tile[k][t];
      uint4 gq;
      gq.x = pack8(f + 0);  gq.y = pack8(f + 8);
      gq.z = pack8(f + 16); gq.w = pack8(f + 24);
      *(uint4*)&dst[(s * 256 + t) * 16] = gq;
      __syncthreads();
    }
  }
}

// stage one slot-major 32-KB tile into LDS: pure linear copy, 4 x 16B/thread
__device__ __forceinline__ void stage_tile(const unsigned char* __restrict__ src,
                                           unsigned char* lds, int t) {
#pragma unroll
  for (int p = 0; p < 4; ++p) {
    int c = p * 512 + t;
    gload_lds16(src + c * 16, lds + c * 16);
  }
}

// ---------------- GEMM: C[M][N] = Xq * Wq^T (fp4 MX, unit scales) ----------
__global__ __launch_bounds__(512, 2) void gemm_fp4_kernel(
    const unsigned char* __restrict__ Aq,
    const unsigned char* __restrict__ Bq,
    const float* __restrict__ alpha,
    const float* __restrict__ betta,
    const float* __restrict__ gamma,
    float* __restrict__ C) {
  __shared__ __align__(16) unsigned char smem[131072];  // 2 x (sA 32KB + sB 32KB)

  const int t = threadIdx.x;
  const int lane = t & 63;
  const int l31 = lane & 31;
  const int lhi = lane >> 5;
  const int w = t >> 6;          // 0..7
  const int wr = w >> 2;         // 0..1  (128-row half)
  const int wc = w & 3;          // 0..3  (64-col quarter)

  // bijective XCD swizzle: 256 blocks, XCD x owns bn panel x
  const int bid = blockIdx.x;
  const int bn = bid & 7;
  const int bm = bid >> 3;
  const int row0 = bm * 256;
  const int col0 = bn * 256;

  const unsigned char* Abase = Aq + (size_t)bm * PANEL_BYTES;
  const unsigned char* Bbase = Bq + (size_t)bn * PANEL_BYTES;

  f32x16 acc[4][2];
#pragma unroll
  for (int fm = 0; fm < 4; ++fm)
#pragma unroll
    for (int fn = 0; fn < 2; ++fn)
#pragma unroll
      for (int r = 0; r < 16; ++r) acc[fm][fn][r] = 0.f;

  // prologue: stage K-tile 0 into buf0, drain, barrier
  stage_tile(Abase, &smem[0], t);
  stage_tile(Bbase, &smem[32768], t);
  asm volatile("s_waitcnt vmcnt(0)" ::: "memory");
  __builtin_amdgcn_s_barrier();

  for (int kt = 0; kt < NT; ++kt) {
    const int cur = kt & 1;
    const unsigned char* pA = &smem[cur * 65536];
    const unsigned char* pB = pA + 32768;

#pragma unroll
    for (int kk = 0; kk < 4; ++kk) {
      // ds-read the 6 fragments for this k-sub-iter (contiguous, conflict-free)
      const int g = kk * 2 + lhi;
      i32x4 a4[4], b4[2];
#pragma unroll
      for (int fm = 0; fm < 4; ++fm)
        a4[fm] = *(const i32x4*)&pA[(g * 256 + wr * 128 + fm * 32 + l31) * 16];
#pragma unroll
      for (int fn = 0; fn < 2; ++fn)
        b4[fn] = *(const i32x4*)&pB[(g * 256 + wc * 64 + fn * 32 + l31) * 16];

      // early stage-issue for next tile so tile-end vmcnt(0) has MFMA cover
      if (kk == 0 && kt + 1 < NT)
        stage_tile(Abase + (kt + 1) * TILE_BYTES, &smem[(cur ^ 1) * 65536], t);
      if (kk == 1 && kt + 1 < NT)
        stage_tile(Bbase + (kt + 1) * TILE_BYTES, &smem[(cur ^ 1) * 65536 + 32768], t);

      __builtin_amdgcn_s_barrier();
      asm volatile("s_waitcnt lgkmcnt(0)" ::: "memory");
      __builtin_amdgcn_sched_barrier(0);
      __builtin_amdgcn_s_setprio(1);
#pragma unroll
      for (int fm = 0; fm < 4; ++fm) {
        i32x8 av = pad8(a4[fm]);
#pragma unroll
        for (int fn = 0; fn < 2; ++fn)
          acc[fm][fn] = __builtin_amdgcn_mfma_scale_f32_32x32x64_f8f6f4(
              av, pad8(b4[fn]), acc[fm][fn], 4, 4,   // cbsz=fp4, blgp=fp4
              0, 0x7F7F7F7F, 0, 0x7F7F7F7F);         // unit E8M0 scales
      }
      __builtin_amdgcn_s_setprio(0);
      // no second barrier: waves may drift within the tile (reads-only buffer)
    }
    // tile boundary: all stage loads for kt+1 must have landed (all waves)
    asm volatile("s_waitcnt vmcnt(0)" ::: "memory");
    __builtin_amdgcn_s_barrier();
  }

  // epilogue: scale[col] = relu(alpha)*relu(betta[col/64])*relu(gamma[col%64])
  const float ra = fmaxf(alpha[0], 0.0f);
#pragma unroll
  for (int fn = 0; fn < 2; ++fn) {
    const int col = col0 + wc * 64 + fn * 32 + l31;
    const float sc = ra * fmaxf(betta[col >> 6], 0.0f) * fmaxf(gamma[col & 63], 0.0f);
#pragma unroll
    for (int fm = 0; fm < 4; ++fm) {
      const int rbase = row0 + wr * 128 + fm * 32 + 4 * lhi;
#pragma unroll
      for (int r = 0; r < 16; ++r) {
        const int row = rbase + (r & 3) + 8 * (r >> 2);
        C[(size_t)row * N_DIM + col] = acc[fm][fn][r] * sc;
      }
    }
  }
}

extern "C" void kernel_launch(void* const* d_in, const int* in_sizes, int n_in,
                              void* d_out, int out_size, void* d_ws, size_t ws_size,
                              hipStream_t stream) {
  const float* X = (const float*)d_in[0];      // [8192][4096]
  const float* W = (const float*)d_in[1];      // [4096][2048]
  const float* alpha = (const float*)d_in[2];  // [1]
  const float* betta = (const float*)d_in[3];  // [32]
  const float* gamma = (const float*)d_in[4];  // [64]
  float* out = (float*)d_out;                  // [8192][2048]

  unsigned char* Xq = (unsigned char*)d_ws;                      // 16 MiB
  unsigned char* Wq = Xq + (size_t)(M_DIM / 256) * PANEL_BYTES;  // 4 MiB

  binXW_kernel<<<640, 256, 0, stream>>>(X, W, Xq, Wq);
  gemm_fp4_kernel<<<(M_DIM / 256) * (N_DIM / 256), 512, 0, stream>>>(
      Xq, Wq, alpha, betta, gamma, out);
}

// Round 5
// 76.050 us; speedup vs baseline: 1.0688x; 1.0688x over previous
//
#include <hip/hip_runtime.h>

// BinaryLinearLayer: C = (sign(X) @ sign(W)) * (relu(alpha)*outer(relu(betta),relu(gamma))).flatten()
// M=8192, K=4096, N=2048.
// fp4 e2m1 (+/-1, 0 exact; unit E8M0 scales) -> mfma_scale_f32_32x32x64_f8f6f4.
// Operands SLOT-MAJOR per 256row x 256k tile: [panel][kt][slot 0..7][row 0..255] x 16B.
// GEMM staging = linear 32KB copy; ds_reads contiguous 512B/half-wave (conflict-free).

#define M_DIM 8192
#define K_DIM 4096
#define N_DIM 2048
#define NT    (K_DIM / 256)            // 16 K-tiles of 256 k-elems
#define TILE_BYTES 32768               // 8 slots x 256 rows x 16 B
#define PANEL_BYTES (NT * TILE_BYTES)  // 512 KB per 256-row panel

typedef int i32x4 __attribute__((ext_vector_type(4)));
typedef int i32x8 __attribute__((ext_vector_type(8)));
typedef float f32x16 __attribute__((ext_vector_type(16)));

__device__ __forceinline__ unsigned int nib4(float x) {
  // sign(x) as fp4 e2m1 nibble: +1 -> 0x2, -1 -> 0xA, 0 -> 0x0
  unsigned int s = (__float_as_uint(x) >> 28) & 0x8u;
  return x == 0.0f ? 0u : (0x2u | s);
}

__device__ __forceinline__ unsigned int pack8(const float* f) {
  unsigned int p = 0;
#pragma unroll
  for (int j = 0; j < 8; ++j) p |= nib4(f[j]) << (4 * j);
  return p;
}

__device__ __forceinline__ void gload_lds16(const void* g, void* lds) {
  __builtin_amdgcn_global_load_lds(
      (const __attribute__((address_space(1))) unsigned int*)g,
      (__attribute__((address_space(3))) unsigned int*)lds, 16, 0, 0);
}

__device__ __forceinline__ i32x8 pad8(i32x4 v) {
  i32x8 r;
  r[0] = v[0]; r[1] = v[1]; r[2] = v[2]; r[3] = v[3];
  r[4] = 0; r[5] = 0; r[6] = 0; r[7] = 0;
  return r;
}

// ---- binX: X f32 [M][K] -> Xq slot-major, coalesced, no LDS ----
// 4096 blocks: row-group rg = bid>>4 (32 rows), kt = bid&15. 1 granule/thread.
__global__ __launch_bounds__(256) void binX_kernel(
    const float* __restrict__ X, unsigned char* __restrict__ Xq) {
  const int t = threadIdx.x;
  const int s = t >> 5;        // 0..7  k-slot
  const int r = t & 31;        // 0..31 row within group
  const int rg = blockIdx.x >> 4;
  const int kt = blockIdx.x & 15;
  const int row = rg * 32 + r;
  const int panel = row >> 8;

  const float* src = X + (size_t)row * K_DIM + kt * 256 + s * 32;
  float f[32];
#pragma unroll
  for (int i = 0; i < 8; ++i)
    *(float4*)&f[i * 4] = *(const float4*)&src[i * 4];
  uint4 gq;
  gq.x = pack8(f + 0);  gq.y = pack8(f + 8);
  gq.z = pack8(f + 16); gq.w = pack8(f + 24);
  unsigned char* dst = Xq + (size_t)panel * PANEL_BYTES + kt * TILE_BYTES +
                       ((size_t)s * 256 + (row & 255)) * 16;
  *(uint4*)dst = gq;
}

// ---- binW: W f32 [K][N] -> Wq transpose slot-major, LDS stripe transpose ----
// 1024 blocks: q = bid>>7, kt = (bid>>3)&15, s = bid&7. 1 granule/thread.
__global__ __launch_bounds__(256) void binW_kernel(
    const float* __restrict__ W, unsigned char* __restrict__ Wq) {
  __shared__ float tile[32][260];   // row stride 1040B: 16B-aligned, k-reads conflict-free
  const int t = threadIdx.x;
  const int q = blockIdx.x >> 7;
  const int kt = (blockIdx.x >> 3) & 15;
  const int s = blockIdx.x & 7;

  // load stripe W[kt*256 + s*32 + 0..31][q*256 + 0..255] coalesced
#pragma unroll
  for (int i = 0; i < 8; ++i) {
    int row = i * 4 + (t >> 6);
    int col4 = (t & 63) * 4;
    *(float4*)&tile[row][col4] =
        *(const float4*)&W[(size_t)(kt * 256 + s * 32 + row) * N_DIM + q * 256 + col4];
  }
  __syncthreads();
  float f[32];
#pragma unroll
  for (int k = 0; k < 32; ++k) f[k] = tile[k][t];
  uint4 gq;
  gq.x = pack8(f + 0);  gq.y = pack8(f + 8);
  gq.z = pack8(f + 16); gq.w = pack8(f + 24);
  unsigned char* dst = Wq + (size_t)q * PANEL_BYTES + kt * TILE_BYTES +
                       ((size_t)s * 256 + t) * 16;
  *(uint4*)dst = gq;
}

// stage one slot-major 32-KB tile into LDS: pure linear copy, 4 x 16B/thread
__device__ __forceinline__ void stage_tile(const unsigned char* __restrict__ src,
                                           unsigned char* lds, int t) {
#pragma unroll
  for (int p = 0; p < 4; ++p) {
    int c = p * 512 + t;
    gload_lds16(src + c * 16, lds + c * 16);
  }
}

// ---------------- GEMM: C[M][N] = Xq * Wq^T (fp4 MX, unit scales) ----------
__global__ __launch_bounds__(512, 2) void gemm_fp4_kernel(
    const unsigned char* __restrict__ Aq,
    const unsigned char* __restrict__ Bq,
    const float* __restrict__ alpha,
    const float* __restrict__ betta,
    const float* __restrict__ gamma,
    float* __restrict__ C) {
  __shared__ __align__(16) unsigned char smem[131072];  // 2 x (sA 32KB + sB 32KB)

  const int t = threadIdx.x;
  const int lane = t & 63;
  const int l31 = lane & 31;
  const int lhi = lane >> 5;
  const int w = t >> 6;          // 0..7
  const int wr = w >> 2;         // 0..1  (128-row half)
  const int wc = w & 3;          // 0..3  (64-col quarter)

  // XCD swizzle: 256 blocks, XCD x owns bn panel x (Wq panel L2-resident)
  const int bid = blockIdx.x;
  const int bn = bid & 7;
  const int bm = bid >> 3;
  const int row0 = bm * 256;
  const int col0 = bn * 256;

  const unsigned char* Abase = Aq + (size_t)bm * PANEL_BYTES;
  const unsigned char* Bbase = Bq + (size_t)bn * PANEL_BYTES;

  f32x16 acc[4][2];
#pragma unroll
  for (int fm = 0; fm < 4; ++fm)
#pragma unroll
    for (int fn = 0; fn < 2; ++fn)
#pragma unroll
      for (int r = 0; r < 16; ++r) acc[fm][fn][r] = 0.f;

  // prologue: stage K-tile 0 into buf0, drain, barrier
  stage_tile(Abase, &smem[0], t);
  stage_tile(Bbase, &smem[32768], t);
  asm volatile("s_waitcnt vmcnt(0)" ::: "memory");
  __builtin_amdgcn_s_barrier();

  for (int kt = 0; kt < NT; ++kt) {
    const int cur = kt & 1;
    const unsigned char* pA = &smem[cur * 65536];
    const unsigned char* pB = pA + 32768;

#pragma unroll
    for (int kk = 0; kk < 4; ++kk) {
      // ds-read the 6 fragments for this k-sub-iter (contiguous, conflict-free)
      const int g = kk * 2 + lhi;
      i32x4 a4[4], b4[2];
#pragma unroll
      for (int fm = 0; fm < 4; ++fm)
        a4[fm] = *(const i32x4*)&pA[(g * 256 + wr * 128 + fm * 32 + l31) * 16];
#pragma unroll
      for (int fn = 0; fn < 2; ++fn)
        b4[fn] = *(const i32x4*)&pB[(g * 256 + wc * 64 + fn * 32 + l31) * 16];

      // early stage-issue for next tile so tile-end vmcnt(0) has MFMA cover
      if (kk == 0 && kt + 1 < NT)
        stage_tile(Abase + (kt + 1) * TILE_BYTES, &smem[(cur ^ 1) * 65536], t);
      if (kk == 1 && kt + 1 < NT)
        stage_tile(Bbase + (kt + 1) * TILE_BYTES, &smem[(cur ^ 1) * 65536 + 32768], t);

      __builtin_amdgcn_s_barrier();
      asm volatile("s_waitcnt lgkmcnt(0)" ::: "memory");
      __builtin_amdgcn_sched_barrier(0);
      __builtin_amdgcn_s_setprio(1);
#pragma unroll
      for (int fm = 0; fm < 4; ++fm) {
        i32x8 av = pad8(a4[fm]);
#pragma unroll
        for (int fn = 0; fn < 2; ++fn)
          acc[fm][fn] = __builtin_amdgcn_mfma_scale_f32_32x32x64_f8f6f4(
              av, pad8(b4[fn]), acc[fm][fn], 4, 4,   // cbsz=fp4, blgp=fp4
              0, 0x7F7F7F7F, 0, 0x7F7F7F7F);         // unit E8M0 scales
      }
      __builtin_amdgcn_s_setprio(0);
      // no second barrier: waves may drift within the tile (read-only buffer)
    }
    // tile boundary: all stage loads for kt+1 must have landed (all waves)
    asm volatile("s_waitcnt vmcnt(0)" ::: "memory");
    __builtin_amdgcn_s_barrier();
  }

  // epilogue: scale[col] = relu(alpha)*relu(betta[col/64])*relu(gamma[col%64])
  const float ra = fmaxf(alpha[0], 0.0f);
#pragma unroll
  for (int fn = 0; fn < 2; ++fn) {
    const int col = col0 + wc * 64 + fn * 32 + l31;
    const float sc = ra * fmaxf(betta[col >> 6], 0.0f) * fmaxf(gamma[col & 63], 0.0f);
#pragma unroll
    for (int fm = 0; fm < 4; ++fm) {
      const int rbase = row0 + wr * 128 + fm * 32 + 4 * lhi;
#pragma unroll
      for (int r = 0; r < 16; ++r) {
        const int row = rbase + (r & 3) + 8 * (r >> 2);
        C[(size_t)row * N_DIM + col] = acc[fm][fn][r] * sc;
      }
    }
  }
}

extern "C" void kernel_launch(void* const* d_in, const int* in_sizes, int n_in,
                              void* d_out, int out_size, void* d_ws, size_t ws_size,
                              hipStream_t stream) {
  const float* X = (const float*)d_in[0];      // [8192][4096]
  const float* W = (const float*)d_in[1];      // [4096][2048]
  const float* alpha = (const float*)d_in[2];  // [1]
  const float* betta = (const float*)d_in[3];  // [32]
  const float* gamma = (const float*)d_in[4];  // [64]
  float* out = (float*)d_out;                  // [8192][2048]

  unsigned char* Xq = (unsigned char*)d_ws;                      // 16 MiB
  unsigned char* Wq = Xq + (size_t)(M_DIM / 256) * PANEL_BYTES;  // 4 MiB

  binW_kernel<<<1024, 256, 0, stream>>>(W, Wq);
  binX_kernel<<<4096, 256, 0, stream>>>(X, Xq);
  gemm_fp4_kernel<<<(M_DIM / 256) * (N_DIM / 256), 512, 0, stream>>>(
      Xq, Wq, alpha, betta, gamma, out);
}

// Round 6
// 75.340 us; speedup vs baseline: 1.0789x; 1.0094x over previous
//
#include <hip/hip_runtime.h>

// BinaryLinearLayer: C = (sign(X) @ sign(W)) * (relu(alpha)*outer(relu(betta),relu(gamma))).flatten()
// M=8192, K=4096, N=2048.
// fp4 e2m1 (+/-1, 0 exact; unit E8M0 scales) -> mfma_scale_f32_32x32x64_f8f6f4.
// Operands SLOT-MAJOR per 256row x 256k tile: [panel][kt][slot 0..7][row 0..255] x 16B.
// GEMM: register-pipelined frag reads (ds_read kk+1 under MFMA kk), 1 barrier/tile.

#define M_DIM 8192
#define K_DIM 4096
#define N_DIM 2048
#define NT    (K_DIM / 256)            // 16 K-tiles of 256 k-elems
#define TILE_BYTES 32768               // 8 slots x 256 rows x 16 B
#define PANEL_BYTES (NT * TILE_BYTES)  // 512 KB per 256-row panel

typedef int i32x4 __attribute__((ext_vector_type(4)));
typedef int i32x8 __attribute__((ext_vector_type(8)));
typedef float f32x16 __attribute__((ext_vector_type(16)));

__device__ __forceinline__ unsigned int nib4(float x) {
  // sign(x) as fp4 e2m1 nibble: +1 -> 0x2, -1 -> 0xA, 0 -> 0x0
  unsigned int s = (__float_as_uint(x) >> 28) & 0x8u;
  return x == 0.0f ? 0u : (0x2u | s);
}

__device__ __forceinline__ unsigned int pack8(const float* f) {
  unsigned int p = 0;
#pragma unroll
  for (int j = 0; j < 8; ++j) p |= nib4(f[j]) << (4 * j);
  return p;
}

__device__ __forceinline__ void gload_lds16(const void* g, void* lds) {
  __builtin_amdgcn_global_load_lds(
      (const __attribute__((address_space(1))) unsigned int*)g,
      (__attribute__((address_space(3))) unsigned int*)lds, 16, 0, 0);
}

__device__ __forceinline__ i32x8 pad8(i32x4 v) {
  i32x8 r;
  r[0] = v[0]; r[1] = v[1]; r[2] = v[2]; r[3] = v[3];
  r[4] = 0; r[5] = 0; r[6] = 0; r[7] = 0;
  return r;
}

// ---- binX: X f32 [M][K] -> Xq slot-major; coalesced reads via LDS stripe ----
// 4096 blocks: rg = bid>>4 (32 rows), kt = bid&15.
__global__ __launch_bounds__(256) void binX_kernel(
    const float* __restrict__ X, unsigned char* __restrict__ Xq) {
  __shared__ float tile[32][260];   // 1040B row stride: 16B-aligned
  const int t = threadIdx.x;
  const int rg = blockIdx.x >> 4;
  const int kt = blockIdx.x & 15;
  const int lrow = t >> 6;          // 0..3
  const int col4 = (t & 63) * 4;
#pragma unroll
  for (int i = 0; i < 8; ++i)
    *(float4*)&tile[i * 4 + lrow][col4] =
        *(const float4*)&X[(size_t)(rg * 32 + i * 4 + lrow) * K_DIM + kt * 256 + col4];
  __syncthreads();
  const int s = t >> 5;   // 0..7 k-slot
  const int r = t & 31;   // 0..31 row in group
  float f[32];
#pragma unroll
  for (int j = 0; j < 32; ++j) f[j] = tile[r][s * 32 + j];
  uint4 gq;
  gq.x = pack8(f + 0);  gq.y = pack8(f + 8);
  gq.z = pack8(f + 16); gq.w = pack8(f + 24);
  const int row = rg * 32 + r;
  unsigned char* dst = Xq + (size_t)(row >> 8) * PANEL_BYTES + kt * TILE_BYTES +
                       ((size_t)s * 256 + (row & 255)) * 16;
  *(uint4*)dst = gq;
}

// ---- binW: W f32 [K][N] -> Wq transpose slot-major, LDS stripe transpose ----
// 1024 blocks: q = bid>>7, kt = (bid>>3)&15, s = bid&7. 1 granule/thread.
__global__ __launch_bounds__(256) void binW_kernel(
    const float* __restrict__ W, unsigned char* __restrict__ Wq) {
  __shared__ float tile[32][260];
  const int t = threadIdx.x;
  const int q = blockIdx.x >> 7;
  const int kt = (blockIdx.x >> 3) & 15;
  const int s = blockIdx.x & 7;
#pragma unroll
  for (int i = 0; i < 8; ++i) {
    int row = i * 4 + (t >> 6);
    int col4 = (t & 63) * 4;
    *(float4*)&tile[row][col4] =
        *(const float4*)&W[(size_t)(kt * 256 + s * 32 + row) * N_DIM + q * 256 + col4];
  }
  __syncthreads();
  float f[32];
#pragma unroll
  for (int k = 0; k < 32; ++k) f[k] = tile[k][t];
  uint4 gq;
  gq.x = pack8(f + 0);  gq.y = pack8(f + 8);
  gq.z = pack8(f + 16); gq.w = pack8(f + 24);
  unsigned char* dst = Wq + (size_t)q * PANEL_BYTES + kt * TILE_BYTES +
                       ((size_t)s * 256 + t) * 16;
  *(uint4*)dst = gq;
}

// stage one slot-major 32-KB tile into LDS: pure linear copy, 4 x 16B/thread
__device__ __forceinline__ void stage_tile(const unsigned char* __restrict__ src,
                                           unsigned char* lds, int t) {
#pragma unroll
  for (int p = 0; p < 4; ++p) {
    int c = p * 512 + t;
    gload_lds16(src + c * 16, lds + c * 16);
  }
}

__device__ __forceinline__ void load_frags(i32x4* a4, i32x4* b4,
                                           const unsigned char* pA,
                                           const unsigned char* pB,
                                           int g, int wr, int wc, int l31) {
#pragma unroll
  for (int fm = 0; fm < 4; ++fm)
    a4[fm] = *(const i32x4*)&pA[(g * 256 + wr * 128 + fm * 32 + l31) * 16];
#pragma unroll
  for (int fn = 0; fn < 2; ++fn)
    b4[fn] = *(const i32x4*)&pB[(g * 256 + wc * 64 + fn * 32 + l31) * 16];
}

// ---------------- GEMM: C[M][N] = Xq * Wq^T (fp4 MX, unit scales) ----------
__global__ __launch_bounds__(512, 2) void gemm_fp4_kernel(
    const unsigned char* __restrict__ Aq,
    const unsigned char* __restrict__ Bq,
    const float* __restrict__ alpha,
    const float* __restrict__ betta,
    const float* __restrict__ gamma,
    float* __restrict__ C) {
  __shared__ __align__(16) unsigned char smem[131072];  // 2 x (sA 32KB + sB 32KB)

  const int t = threadIdx.x;
  const int lane = t & 63;
  const int l31 = lane & 31;
  const int lhi = lane >> 5;
  const int w = t >> 6;          // 0..7
  const int wr = w >> 2;         // 0..1  (128-row half)
  const int wc = w & 3;          // 0..3  (64-col quarter)

  // XCD swizzle: 256 blocks, XCD x owns bn panel x (Wq panel L2-resident)
  const int bid = blockIdx.x;
  const int bn = bid & 7;
  const int bm = bid >> 3;
  const int row0 = bm * 256;
  const int col0 = bn * 256;

  const unsigned char* Abase = Aq + (size_t)bm * PANEL_BYTES;
  const unsigned char* Bbase = Bq + (size_t)bn * PANEL_BYTES;

  f32x16 acc[4][2];
#pragma unroll
  for (int fm = 0; fm < 4; ++fm)
#pragma unroll
    for (int fn = 0; fn < 2; ++fn)
#pragma unroll
      for (int r = 0; r < 16; ++r) acc[fm][fn][r] = 0.f;

  // prologue: stage K-tile 0 into buf0, drain, barrier
  stage_tile(Abase, &smem[0], t);
  stage_tile(Bbase, &smem[32768], t);
  asm volatile("s_waitcnt vmcnt(0)" ::: "memory");
  __builtin_amdgcn_s_barrier();

  i32x4 a4[2][4], b4[2][2];
  load_frags(a4[0], b4[0], &smem[0], &smem[32768], lhi, wr, wc, l31);  // kk=0

  for (int kt = 0; kt < NT; ++kt) {
    const int cur = kt & 1;
    const unsigned char* pA = &smem[cur * 65536];
    const unsigned char* pB = pA + 32768;

#pragma unroll
    for (int kk = 0; kk < 4; ++kk) {
      const int pb = kk & 1, pn = pb ^ 1;
      // frags[pb] were issued one phase ago (covered by previous MFMA cluster)
      asm volatile("s_waitcnt lgkmcnt(0)" ::: "memory");
      __builtin_amdgcn_sched_barrier(0);
      // early stage-issue for next tile (targets the other LDS buffer)
      if (kk == 0 && kt + 1 < NT)
        stage_tile(Abase + (kt + 1) * TILE_BYTES, &smem[(cur ^ 1) * 65536], t);
      if (kk == 1 && kt + 1 < NT)
        stage_tile(Bbase + (kt + 1) * TILE_BYTES, &smem[(cur ^ 1) * 65536 + 32768], t);
      // prefetch next phase's fragments into the other reg buffer
      if (kk < 3)
        load_frags(a4[pn], b4[pn], pA, pB, (kk + 1) * 2 + lhi, wr, wc, l31);
      __builtin_amdgcn_sched_barrier(0);
      __builtin_amdgcn_s_setprio(1);
#pragma unroll
      for (int fm = 0; fm < 4; ++fm) {
        i32x8 av = pad8(a4[pb][fm]);
#pragma unroll
        for (int fn = 0; fn < 2; ++fn)
          acc[fm][fn] = __builtin_amdgcn_mfma_scale_f32_32x32x64_f8f6f4(
              av, pad8(b4[pb][fn]), acc[fm][fn], 4, 4,   // cbsz=fp4, blgp=fp4
              0, 0x7F7F7F7F, 0, 0x7F7F7F7F);             // unit E8M0 scales
      }
      __builtin_amdgcn_s_setprio(0);
    }
    // tile boundary: own stage loads landed; barrier syncs all waves
    asm volatile("s_waitcnt vmcnt(0)" ::: "memory");
    __builtin_amdgcn_s_barrier();
    if (kt + 1 < NT) {
      const unsigned char* nA = &smem[((kt + 1) & 1) * 65536];
      load_frags(a4[0], b4[0], nA, nA + 32768, lhi, wr, wc, l31);  // next kk=0
    }
  }

  // epilogue: scale[col] = relu(alpha)*relu(betta[col/64])*relu(gamma[col%64])
  const float ra = fmaxf(alpha[0], 0.0f);
#pragma unroll
  for (int fn = 0; fn < 2; ++fn) {
    const int col = col0 + wc * 64 + fn * 32 + l31;
    const float sc = ra * fmaxf(betta[col >> 6], 0.0f) * fmaxf(gamma[col & 63], 0.0f);
#pragma unroll
    for (int fm = 0; fm < 4; ++fm) {
      const int rbase = row0 + wr * 128 + fm * 32 + 4 * lhi;
#pragma unroll
      for (int r = 0; r < 16; ++r) {
        const int row = rbase + (r & 3) + 8 * (r >> 2);
        C[(size_t)row * N_DIM + col] = acc[fm][fn][r] * sc;
      }
    }
  }
}

extern "C" void kernel_launch(void* const* d_in, const int* in_sizes, int n_in,
                              void* d_out, int out_size, void* d_ws, size_t ws_size,
                              hipStream_t stream) {
  const float* X = (const float*)d_in[0];      // [8192][4096]
  const float* W = (const float*)d_in[1];      // [4096][2048]
  const float* alpha = (const float*)d_in[2];  // [1]
  const float* betta = (const float*)d_in[3];  // [32]
  const float* gamma = (const float*)d_in[4];  // [64]
  float* out = (float*)d_out;                  // [8192][2048]

  unsigned char* Xq = (unsigned char*)d_ws;                      // 16 MiB
  unsigned char* Wq = Xq + (size_t)(M_DIM / 256) * PANEL_BYTES;  // 4 MiB

  binW_kernel<<<1024, 256, 0, stream>>>(W, Wq);
  binX_kernel<<<4096, 256, 0, stream>>>(X, Xq);
  gemm_fp4_kernel<<<(M_DIM / 256) * (N_DIM / 256), 512, 0, stream>>>(
      Xq, Wq, alpha, betta, gamma, out);
}

// Round 7
// 74.929 us; speedup vs baseline: 1.0848x; 1.0055x over previous
//
#include <hip/hip_runtime.h>

// BinaryLinearLayer: C = (sign(X) @ sign(W)) * (relu(alpha)*outer(relu(betta),relu(gamma))).flatten()
// M=8192, K=4096, N=2048.
// fp4 e2m1 (+/-1, 0 exact; unit E8M0 scales) -> mfma_scale_f32_32x32x64_f8f6f4.
// Operands SLOT-MAJOR per 256row x 256k tile: [panel][kt][slot 0..7][row 0..255] x 16B.
// GEMM: register-pipelined frag reads, 1 barrier/tile, 2-D XCD tile ownership
// (each XCD owns 4 bm x 8 bn -> per-K-step L3 fetch 384KB/XCD, rest L2 hits).

#define M_DIM 8192
#define K_DIM 4096
#define N_DIM 2048
#define NT    (K_DIM / 256)            // 16 K-tiles of 256 k-elems
#define TILE_BYTES 32768               // 8 slots x 256 rows x 16 B
#define PANEL_BYTES (NT * TILE_BYTES)  // 512 KB per 256-row panel

typedef int i32x4 __attribute__((ext_vector_type(4)));
typedef int i32x8 __attribute__((ext_vector_type(8)));
typedef float f32x16 __attribute__((ext_vector_type(16)));

__device__ __forceinline__ unsigned int nib4(float x) {
  // sign(x) as fp4 e2m1 nibble: +1 -> 0x2, -1 -> 0xA, 0 -> 0x0
  unsigned int s = (__float_as_uint(x) >> 28) & 0x8u;
  return x == 0.0f ? 0u : (0x2u | s);
}

__device__ __forceinline__ unsigned int pack8(const float* f) {
  unsigned int p = 0;
#pragma unroll
  for (int j = 0; j < 8; ++j) p |= nib4(f[j]) << (4 * j);
  return p;
}

__device__ __forceinline__ void gload_lds16(const void* g, void* lds) {
  __builtin_amdgcn_global_load_lds(
      (const __attribute__((address_space(1))) unsigned int*)g,
      (__attribute__((address_space(3))) unsigned int*)lds, 16, 0, 0);
}

__device__ __forceinline__ i32x8 pad8(i32x4 v) {
  i32x8 r;
  r[0] = v[0]; r[1] = v[1]; r[2] = v[2]; r[3] = v[3];
  r[4] = 0; r[5] = 0; r[6] = 0; r[7] = 0;
  return r;
}

// ---- binX: X f32 [M][K] -> Xq slot-major; coalesced reads via LDS stripe ----
// 4096 blocks: rg = bid>>4 (32 rows), kt = bid&15.
__global__ __launch_bounds__(256) void binX_kernel(
    const float* __restrict__ X, unsigned char* __restrict__ Xq) {
  __shared__ float tile[32][260];   // 1040B row stride: 16B-aligned
  const int t = threadIdx.x;
  const int rg = blockIdx.x >> 4;
  const int kt = blockIdx.x & 15;
  const int lrow = t >> 6;          // 0..3
  const int col4 = (t & 63) * 4;
#pragma unroll
  for (int i = 0; i < 8; ++i)
    *(float4*)&tile[i * 4 + lrow][col4] =
        *(const float4*)&X[(size_t)(rg * 32 + i * 4 + lrow) * K_DIM + kt * 256 + col4];
  __syncthreads();
  const int s = t >> 5;   // 0..7 k-slot
  const int r = t & 31;   // 0..31 row in group
  float f[32];
#pragma unroll
  for (int j = 0; j < 32; ++j) f[j] = tile[r][s * 32 + j];
  uint4 gq;
  gq.x = pack8(f + 0);  gq.y = pack8(f + 8);
  gq.z = pack8(f + 16); gq.w = pack8(f + 24);
  const int row = rg * 32 + r;
  unsigned char* dst = Xq + (size_t)(row >> 8) * PANEL_BYTES + kt * TILE_BYTES +
                       ((size_t)s * 256 + (row & 255)) * 16;
  *(uint4*)dst = gq;
}

// ---- binW: W f32 [K][N] -> Wq transpose slot-major, LDS stripe transpose ----
// 1024 blocks: q = bid>>7, kt = (bid>>3)&15, s = bid&7. 1 granule/thread.
__global__ __launch_bounds__(256) void binW_kernel(
    const float* __restrict__ W, unsigned char* __restrict__ Wq) {
  __shared__ float tile[32][260];
  const int t = threadIdx.x;
  const int q = blockIdx.x >> 7;
  const int kt = (blockIdx.x >> 3) & 15;
  const int s = blockIdx.x & 7;
#pragma unroll
  for (int i = 0; i < 8; ++i) {
    int row = i * 4 + (t >> 6);
    int col4 = (t & 63) * 4;
    *(float4*)&tile[row][col4] =
        *(const float4*)&W[(size_t)(kt * 256 + s * 32 + row) * N_DIM + q * 256 + col4];
  }
  __syncthreads();
  float f[32];
#pragma unroll
  for (int k = 0; k < 32; ++k) f[k] = tile[k][t];
  uint4 gq;
  gq.x = pack8(f + 0);  gq.y = pack8(f + 8);
  gq.z = pack8(f + 16); gq.w = pack8(f + 24);
  unsigned char* dst = Wq + (size_t)q * PANEL_BYTES + kt * TILE_BYTES +
                       ((size_t)s * 256 + t) * 16;
  *(uint4*)dst = gq;
}

// stage one slot-major 32-KB tile into LDS: pure linear copy, 4 x 16B/thread
__device__ __forceinline__ void stage_tile(const unsigned char* __restrict__ src,
                                           unsigned char* lds, int t) {
#pragma unroll
  for (int p = 0; p < 4; ++p) {
    int c = p * 512 + t;
    gload_lds16(src + c * 16, lds + c * 16);
  }
}

__device__ __forceinline__ void load_frags(i32x4* a4, i32x4* b4,
                                           const unsigned char* pA,
                                           const unsigned char* pB,
                                           int g, int wr, int wc, int l31) {
#pragma unroll
  for (int fm = 0; fm < 4; ++fm)
    a4[fm] = *(const i32x4*)&pA[(g * 256 + wr * 128 + fm * 32 + l31) * 16];
#pragma unroll
  for (int fn = 0; fn < 2; ++fn)
    b4[fn] = *(const i32x4*)&pB[(g * 256 + wc * 64 + fn * 32 + l31) * 16];
}

// ---------------- GEMM: C[M][N] = Xq * Wq^T (fp4 MX, unit scales) ----------
__global__ __launch_bounds__(512, 2) void gemm_fp4_kernel(
    const unsigned char* __restrict__ Aq,
    const unsigned char* __restrict__ Bq,
    const float* __restrict__ alpha,
    const float* __restrict__ betta,
    const float* __restrict__ gamma,
    float* __restrict__ C) {
  __shared__ __align__(16) unsigned char smem[131072];  // 2 x (sA 32KB + sB 32KB)

  const int t = threadIdx.x;
  const int lane = t & 63;
  const int l31 = lane & 31;
  const int lhi = lane >> 5;
  const int w = t >> 6;          // 0..7
  const int wr = w >> 2;         // 0..1  (128-row half)
  const int wc = w & 3;          // 0..3  (64-col quarter)

  // 2-D XCD ownership: XCD x (= bid%8) owns bm in {4x..4x+3}, all 8 bn.
  // Per K-step, XCD fetches only 12 distinct 32KB tiles from L3; all
  // intra-XCD re-reads hit the 4MB L2. Bijective bit-field decode.
  const int bid = blockIdx.x;
  const int bm = (bid & 7) * 4 + (bid >> 6);
  const int bn = (bid >> 3) & 7;
  const int row0 = bm * 256;
  const int col0 = bn * 256;

  const unsigned char* Abase = Aq + (size_t)bm * PANEL_BYTES;
  const unsigned char* Bbase = Bq + (size_t)bn * PANEL_BYTES;

  f32x16 acc[4][2];
#pragma unroll
  for (int fm = 0; fm < 4; ++fm)
#pragma unroll
    for (int fn = 0; fn < 2; ++fn)
#pragma unroll
      for (int r = 0; r < 16; ++r) acc[fm][fn][r] = 0.f;

  // prologue: stage K-tile 0 into buf0, drain, barrier
  stage_tile(Abase, &smem[0], t);
  stage_tile(Bbase, &smem[32768], t);
  asm volatile("s_waitcnt vmcnt(0)" ::: "memory");
  __builtin_amdgcn_s_barrier();

  i32x4 a4[2][4], b4[2][2];
  load_frags(a4[0], b4[0], &smem[0], &smem[32768], lhi, wr, wc, l31);  // kk=0

  for (int kt = 0; kt < NT; ++kt) {
    const int cur = kt & 1;
    const unsigned char* pA = &smem[cur * 65536];
    const unsigned char* pB = pA + 32768;

#pragma unroll
    for (int kk = 0; kk < 4; ++kk) {
      const int pb = kk & 1, pn = pb ^ 1;
      // frags[pb] were issued one phase ago (covered by previous MFMA cluster)
      asm volatile("s_waitcnt lgkmcnt(0)" ::: "memory");
      __builtin_amdgcn_sched_barrier(0);
      // early stage-issue for next tile (targets the other LDS buffer)
      if (kk == 0 && kt + 1 < NT) {
        stage_tile(Abase + (kt + 1) * TILE_BYTES, &smem[(cur ^ 1) * 65536], t);
        stage_tile(Bbase + (kt + 1) * TILE_BYTES, &smem[(cur ^ 1) * 65536 + 32768], t);
      }
      // prefetch next phase's fragments into the other reg buffer
      if (kk < 3)
        load_frags(a4[pn], b4[pn], pA, pB, (kk + 1) * 2 + lhi, wr, wc, l31);
      __builtin_amdgcn_sched_barrier(0);
      __builtin_amdgcn_s_setprio(1);
#pragma unroll
      for (int fm = 0; fm < 4; ++fm) {
        i32x8 av = pad8(a4[pb][fm]);
#pragma unroll
        for (int fn = 0; fn < 2; ++fn)
          acc[fm][fn] = __builtin_amdgcn_mfma_scale_f32_32x32x64_f8f6f4(
              av, pad8(b4[pb][fn]), acc[fm][fn], 4, 4,   // cbsz=fp4, blgp=fp4
              0, 0x7F7F7F7F, 0, 0x7F7F7F7F);             // unit E8M0 scales
      }
      __builtin_amdgcn_s_setprio(0);
    }
    // tile boundary: own stage loads landed; barrier syncs all waves
    asm volatile("s_waitcnt vmcnt(0)" ::: "memory");
    __builtin_amdgcn_s_barrier();
    if (kt + 1 < NT) {
      const unsigned char* nA = &smem[((kt + 1) & 1) * 65536];
      load_frags(a4[0], b4[0], nA, nA + 32768, lhi, wr, wc, l31);  // next kk=0
    }
  }

  // epilogue: scale[col] = relu(alpha)*relu(betta[col/64])*relu(gamma[col%64])
  const float ra = fmaxf(alpha[0], 0.0f);
#pragma unroll
  for (int fn = 0; fn < 2; ++fn) {
    const int col = col0 + wc * 64 + fn * 32 + l31;
    const float sc = ra * fmaxf(betta[col >> 6], 0.0f) * fmaxf(gamma[col & 63], 0.0f);
#pragma unroll
    for (int fm = 0; fm < 4; ++fm) {
      const int rbase = row0 + wr * 128 + fm * 32 + 4 * lhi;
#pragma unroll
      for (int r = 0; r < 16; ++r) {
        const int row = rbase + (r & 3) + 8 * (r >> 2);
        C[(size_t)row * N_DIM + col] = acc[fm][fn][r] * sc;
      }
    }
  }
}

extern "C" void kernel_launch(void* const* d_in, const int* in_sizes, int n_in,
                              void* d_out, int out_size, void* d_ws, size_t ws_size,
                              hipStream_t stream) {
  const float* X = (const float*)d_in[0];      // [8192][4096]
  const float* W = (const float*)d_in[1];      // [4096][2048]
  const float* alpha = (const float*)d_in[2];  // [1]
  const float* betta = (const float*)d_in[3];  // [32]
  const float* gamma = (const float*)d_in[4];  // [64]
  float* out = (float*)d_out;                  // [8192][2048]

  unsigned char* Xq = (unsigned char*)d_ws;                      // 16 MiB
  unsigned char* Wq = Xq + (size_t)(M_DIM / 256) * PANEL_BYTES;  // 4 MiB

  binW_kernel<<<1024, 256, 0, stream>>>(W, Wq);
  binX_kernel<<<4096, 256, 0, stream>>>(X, Xq);
  gemm_fp4_kernel<<<(M_DIM / 256) * (N_DIM / 256), 512, 0, stream>>>(
      Xq, Wq, alpha, betta, gamma, out);
}

// Round 8
// 74.549 us; speedup vs baseline: 1.0903x; 1.0051x over previous
//
#include <hip/hip_runtime.h>

// BinaryLinearLayer: C = (sign(X) @ sign(W)) * (relu(alpha)*outer(relu(betta),relu(gamma))).flatten()
// M=8192, K=4096, N=2048.
// fp4 e2m1 (+/-1, 0 exact; unit E8M0 scales) -> mfma_scale_f32_32x32x64_f8f6f4.
// Operands k-granule-major per panel: A [panel32][kslot128][row256][16B],
//          B [panel16][kslot128][row128][16B]  (kslot = 32 k-elems = 16 B).
// GEMM: 256x128 tile, BK=128, 4 waves (wave tile 128x64), LDS 48 KB dbuf ->
// 2 blocks/CU (sibling block covers boundary stalls + epilogue), grid 512.

#define M_DIM 8192
#define K_DIM 4096
#define N_DIM 2048
#define NT2   (K_DIM / 128)            // 32 K-tiles of 128 k
#define PANEL_A (128 * 256 * 16)       // 512 KB per 256-row A panel
#define PANEL_B (128 * 128 * 16)       // 256 KB per 128-row B panel
#define ATILE 16384                    // 4 kslots x 256 rows x 16B
#define BTILE 8192                     // 4 kslots x 128 rows x 16B

typedef int i32x4 __attribute__((ext_vector_type(4)));
typedef int i32x8 __attribute__((ext_vector_type(8)));
typedef float f32x16 __attribute__((ext_vector_type(16)));

__device__ __forceinline__ unsigned int nib4(float x) {
  // sign(x) as fp4 e2m1 nibble: +1 -> 0x2, -1 -> 0xA, 0 -> 0x0
  unsigned int s = (__float_as_uint(x) >> 28) & 0x8u;
  return x == 0.0f ? 0u : (0x2u | s);
}

__device__ __forceinline__ unsigned int pack8(const float* f) {
  unsigned int p = 0;
#pragma unroll
  for (int j = 0; j < 8; ++j) p |= nib4(f[j]) << (4 * j);
  return p;
}

__device__ __forceinline__ void gload_lds16(const void* g, void* lds) {
  __builtin_amdgcn_global_load_lds(
      (const __attribute__((address_space(1))) unsigned int*)g,
      (__attribute__((address_space(3))) unsigned int*)lds, 16, 0, 0);
}

__device__ __forceinline__ i32x8 pad8(i32x4 v) {
  i32x8 r;
  r[0] = v[0]; r[1] = v[1]; r[2] = v[2]; r[3] = v[3];
  r[4] = 0; r[5] = 0; r[6] = 0; r[7] = 0;
  return r;
}

// ---- binX: X f32 [M][K] -> Xq k-granule-major; coalesced via LDS stripe ----
// 4096 blocks: rg = bid>>4 (32 rows), kc = bid&15 (256-k chunk).
__global__ __launch_bounds__(256) void binX_kernel(
    const float* __restrict__ X, unsigned char* __restrict__ Xq) {
  __shared__ float tile[32][260];   // 1040B row stride: 16B-aligned
  const int t = threadIdx.x;
  const int rg = blockIdx.x >> 4;
  const int kc = blockIdx.x & 15;
  const int lrow = t >> 6;          // 0..3
  const int col4 = (t & 63) * 4;
#pragma unroll
  for (int i = 0; i < 8; ++i)
    *(float4*)&tile[i * 4 + lrow][col4] =
        *(const float4*)&X[(size_t)(rg * 32 + i * 4 + lrow) * K_DIM + kc * 256 + col4];
  __syncthreads();
  const int s = t >> 5;   // 0..7 kslot within chunk
  const int r = t & 31;   // 0..31 row in group
  float f[32];
#pragma unroll
  for (int q = 0; q < 8; ++q)   // float4 reads: 4-way conflict (1.58x), not 8-way
    *(float4*)&f[q * 4] = *(const float4*)&tile[r][s * 32 + q * 4];
  uint4 gq;
  gq.x = pack8(f + 0);  gq.y = pack8(f + 8);
  gq.z = pack8(f + 16); gq.w = pack8(f + 24);
  const int row = rg * 32 + r;
  const int kslot = kc * 8 + s;
  unsigned char* dst = Xq + (size_t)(row >> 8) * PANEL_A +
                       ((size_t)kslot * 256 + (row & 255)) * 16;
  *(uint4*)dst = gq;
}

// ---- binW: W f32 [K][N] -> Wq transpose k-granule-major (128-row panels) ----
// 1024 blocks: q = bid>>7 (256-n stripe), kt = (bid>>3)&15, s = bid&7.
__global__ __launch_bounds__(256) void binW_kernel(
    const float* __restrict__ W, unsigned char* __restrict__ Wq) {
  __shared__ float tile[32][260];
  const int t = threadIdx.x;
  const int q = blockIdx.x >> 7;
  const int kt = (blockIdx.x >> 3) & 15;
  const int s = blockIdx.x & 7;
#pragma unroll
  for (int i = 0; i < 8; ++i) {
    int row = i * 4 + (t >> 6);
    int col4 = (t & 63) * 4;
    *(float4*)&tile[row][col4] =
        *(const float4*)&W[(size_t)(kt * 256 + s * 32 + row) * N_DIM + q * 256 + col4];
  }
  __syncthreads();
  float f[32];
#pragma unroll
  for (int k = 0; k < 32; ++k) f[k] = tile[k][t];   // 2-way: free
  uint4 gq;
  gq.x = pack8(f + 0);  gq.y = pack8(f + 8);
  gq.z = pack8(f + 16); gq.w = pack8(f + 24);
  const int n = q * 256 + t;
  const int kslot = kt * 8 + s;
  unsigned char* dst = Wq + (size_t)(n >> 7) * PANEL_B +
                       ((size_t)kslot * 128 + (n & 127)) * 16;
  *(uint4*)dst = gq;
}

// stage A(16KB)+B(8KB) K-tile into LDS: pure linear copies
__device__ __forceinline__ void stage_tiles(const unsigned char* __restrict__ Asrc,
                                            const unsigned char* __restrict__ Bsrc,
                                            unsigned char* ldsA, int t) {
#pragma unroll
  for (int p = 0; p < 4; ++p) {
    int c = p * 256 + t;
    gload_lds16(Asrc + c * 16, ldsA + c * 16);
  }
#pragma unroll
  for (int p = 0; p < 2; ++p) {
    int c = p * 256 + t;
    gload_lds16(Bsrc + c * 16, ldsA + 16384 + c * 16);
  }
}

__device__ __forceinline__ void load_frags(i32x4* a4, i32x4* b4,
                                           const unsigned char* pA,
                                           const unsigned char* pB,
                                           int g, int wr, int wc, int l31) {
#pragma unroll
  for (int fm = 0; fm < 4; ++fm)
    a4[fm] = *(const i32x4*)&pA[(g * 256 + wr * 128 + fm * 32 + l31) * 16];
#pragma unroll
  for (int fn = 0; fn < 2; ++fn)
    b4[fn] = *(const i32x4*)&pB[(g * 128 + wc * 64 + fn * 32 + l31) * 16];
}

// ---------------- GEMM: C[M][N] = Xq * Wq^T (fp4 MX, unit scales) ----------
__global__ __launch_bounds__(256, 2) void gemm_fp4_kernel(
    const unsigned char* __restrict__ Aq,
    const unsigned char* __restrict__ Bq,
    const float* __restrict__ alpha,
    const float* __restrict__ betta,
    const float* __restrict__ gamma,
    float* __restrict__ C) {
  __shared__ __align__(16) unsigned char smem[49152];  // dbuf x (A 16KB + B 8KB)

  const int t = threadIdx.x;
  const int lane = t & 63;
  const int l31 = lane & 31;
  const int lhi = lane >> 5;
  const int w = t >> 6;          // 0..3
  const int wr = w >> 1;         // 0..1  (128-row half)
  const int wc = w & 1;          // 0..1  (64-col half)

  // 2-D XCD ownership: xcd = bid%8 owns bm in {4x..4x+3} x all 16 bn.
  const int bid = blockIdx.x;
  const int j = bid >> 3;
  const int bm = (bid & 7) * 4 + (j & 3);   // 0..31
  const int bn = j >> 2;                    // 0..15
  const int row0 = bm * 256;
  const int col0 = bn * 128;

  const unsigned char* Abase = Aq + (size_t)bm * PANEL_A;
  const unsigned char* Bbase = Bq + (size_t)bn * PANEL_B;

  f32x16 acc[4][2];
#pragma unroll
  for (int fm = 0; fm < 4; ++fm)
#pragma unroll
    for (int fn = 0; fn < 2; ++fn)
#pragma unroll
      for (int r = 0; r < 16; ++r) acc[fm][fn][r] = 0.f;

  // prologue: stage K-tile 0 into buf0, drain, barrier
  stage_tiles(Abase, Bbase, &smem[0], t);
  asm volatile("s_waitcnt vmcnt(0)" ::: "memory");
  __builtin_amdgcn_s_barrier();

  i32x4 a4[2][4], b4[2][2];
  load_frags(a4[0], b4[0], &smem[0], &smem[16384], lhi, wr, wc, l31);  // ph0

  for (int kt = 0; kt < NT2; ++kt) {
    const int cur = kt & 1;
    const unsigned char* pA = &smem[cur * 24576];
    const unsigned char* pB = pA + 16384;

    // ---- phase 0 ----
    asm volatile("s_waitcnt lgkmcnt(0)" ::: "memory");
    __builtin_amdgcn_sched_barrier(0);
    if (kt + 1 < NT2)
      stage_tiles(Abase + (kt + 1) * ATILE, Bbase + (kt + 1) * BTILE,
                  &smem[(cur ^ 1) * 24576], t);
    load_frags(a4[1], b4[1], pA, pB, 2 + lhi, wr, wc, l31);  // phase-1 frags
    __builtin_amdgcn_sched_barrier(0);
    __builtin_amdgcn_s_setprio(1);
#pragma unroll
    for (int fm = 0; fm < 4; ++fm) {
      i32x8 av = pad8(a4[0][fm]);
#pragma unroll
      for (int fn = 0; fn < 2; ++fn)
        acc[fm][fn] = __builtin_amdgcn_mfma_scale_f32_32x32x64_f8f6f4(
            av, pad8(b4[0][fn]), acc[fm][fn], 4, 4,   // cbsz=fp4, blgp=fp4
            0, 0x7F7F7F7F, 0, 0x7F7F7F7F);            // unit E8M0 scales
    }
    __builtin_amdgcn_s_setprio(0);

    // ---- phase 1 ----
    asm volatile("s_waitcnt lgkmcnt(0)" ::: "memory");
    __builtin_amdgcn_sched_barrier(0);
    __builtin_amdgcn_s_setprio(1);
#pragma unroll
    for (int fm = 0; fm < 4; ++fm) {
      i32x8 av = pad8(a4[1][fm]);
#pragma unroll
      for (int fn = 0; fn < 2; ++fn)
        acc[fm][fn] = __builtin_amdgcn_mfma_scale_f32_32x32x64_f8f6f4(
            av, pad8(b4[1][fn]), acc[fm][fn], 4, 4,
            0, 0x7F7F7F7F, 0, 0x7F7F7F7F);
    }
    __builtin_amdgcn_s_setprio(0);

    // tile boundary: own stage loads landed; barrier syncs all waves
    asm volatile("s_waitcnt vmcnt(0)" ::: "memory");
    __builtin_amdgcn_s_barrier();
    if (kt + 1 < NT2) {
      const unsigned char* nA = &smem[((kt + 1) & 1) * 24576];
      load_frags(a4[0], b4[0], nA, nA + 16384, lhi, wr, wc, l31);  // next ph0
    }
  }

  // epilogue: scale[col] = relu(alpha)*relu(betta[col/64])*relu(gamma[col%64])
  const float ra = fmaxf(alpha[0], 0.0f);
#pragma unroll
  for (int fn = 0; fn < 2; ++fn) {
    const int col = col0 + wc * 64 + fn * 32 + l31;
    const float sc = ra * fmaxf(betta[col >> 6], 0.0f) * fmaxf(gamma[col & 63], 0.0f);
#pragma unroll
    for (int fm = 0; fm < 4; ++fm) {
      const int rbase = row0 + wr * 128 + fm * 32 + 4 * lhi;
#pragma unroll
      for (int r = 0; r < 16; ++r) {
        const int row = rbase + (r & 3) + 8 * (r >> 2);
        C[(size_t)row * N_DIM + col] = acc[fm][fn][r] * sc;
      }
    }
  }
}

extern "C" void kernel_launch(void* const* d_in, const int* in_sizes, int n_in,
                              void* d_out, int out_size, void* d_ws, size_t ws_size,
                              hipStream_t stream) {
  const float* X = (const float*)d_in[0];      // [8192][4096]
  const float* W = (const float*)d_in[1];      // [4096][2048]
  const float* alpha = (const float*)d_in[2];  // [1]
  const float* betta = (const float*)d_in[3];  // [32]
  const float* gamma = (const float*)d_in[4];  // [64]
  float* out = (float*)d_out;                  // [8192][2048]

  unsigned char* Xq = (unsigned char*)d_ws;                    // 16 MiB
  unsigned char* Wq = Xq + (size_t)(M_DIM / 256) * PANEL_A;    // 4 MiB

  binW_kernel<<<1024, 256, 0, stream>>>(W, Wq);
  binX_kernel<<<4096, 256, 0, stream>>>(X, Xq);
  gemm_fp4_kernel<<<(M_DIM / 256) * (N_DIM / 128), 256, 0, stream>>>(
      Xq, Wq, alpha, betta, gamma, out);
}